// Round 5
// baseline (102.778 us; speedup 1.0000x reference)
//
#include <hip/hip_runtime.h>

#define BB 8
#define CC 128
#define HH 64
#define WW 64
#define K2 9
#define NOFF 18
#define HW 4096          // HH*WW
#define NPIX 32768       // BB*HW
#define NQ 4             // channel quarter-groups (blockIdx.y)
#define ROWS 4           // pixel rows per lane
#define WPB 8            // waves per block
#define CPW 4            // channels per wave
#define WPAD 20          // padded weight row (18 used)

// ---------------------------------------------------------------------------
// K-1: transpose offset weights [18][1152] -> wTp[k=(c,j)][WPAD] so the 18
// output weights per k are contiguous (72 B, 16B-aligned) -> 2 s_loads.
// ---------------------------------------------------------------------------
__global__ __launch_bounds__(256) void wtrans_kernel(
    const float* __restrict__ offw, float* __restrict__ wTp)
{
    int i = blockIdx.x * 256 + threadIdx.x;
    if (i >= NOFF * CC * 9) return;
    int k = i / NOFF, o = i - k * NOFF;
    wTp[k * WPAD + o] = offw[(size_t)o * CC * 9 + k];
}

// ---------------------------------------------------------------------------
// K1: offset-conv partials. Grid (128, 4): b = x&7 (XCD-local), strip = x>>3.
// Block = 512 thr = 8 waves; wave wv owns channels q*32 + wv*4 .. +3 and a
// 4-row x 64-col pixel tile (lane = w, ROWS rows). Per k=(c,j): one 72 B
// uniform weight run (SGPR) feeds 18 o x 4 rows = 72 v_fmac. LDS reduce over
// the 8 waves per row -> per-quarter partials.
// ---------------------------------------------------------------------------
__global__ __launch_bounds__(512, 4) void offset_partial_kernel(
    const float* __restrict__ x, const float* __restrict__ wTp,
    float* __restrict__ part)
{
    __shared__ float sred[NOFF * WPB * 64];   // 36.9 KB
    int jx = blockIdx.x;           // 0..127
    int b = jx & 7;
    int h0 = (jx >> 3) * ROWS;
    int q = blockIdx.y;            // 0..3
    int tid = threadIdx.x;
    int w = tid & 63;
    int wv = __builtin_amdgcn_readfirstlane(tid >> 6);  // 0..7
    int cbase = q * 32 + wv * CPW;

    float acc[NOFF][ROWS];
#pragma unroll
    for (int o = 0; o < NOFF; ++o)
#pragma unroll
        for (int r = 0; r < ROWS; ++r) acc[o][r] = 0.f;

#pragma unroll 1
    for (int cc = 0; cc < CPW; ++cc) {
        int c = cbase + cc;
        const float* xp = x + ((size_t)(b * CC + c)) * HW;
        // 6 rows x 3 cols of x around the 4-row tile
        float xr[ROWS + 2][3];
#pragma unroll
        for (int rr = 0; rr < ROWS + 2; ++rr) {
            int hh = h0 + rr - 1;
            bool hok = (unsigned)hh < HH;
#pragma unroll
            for (int dc = 0; dc < 3; ++dc) {
                int ww2 = w + dc - 1;
                bool ok = hok && ((unsigned)ww2 < WW);
                xr[rr][dc] = ok ? xp[hh * WW + ww2] : 0.f;
            }
        }
        const float* wrow = wTp + (size_t)c * 9 * WPAD;
#pragma unroll
        for (int jj = 0; jj < 9; ++jj) {
            const int dh = jj / 3, dw = jj % 3;     // compile-time
            const float* wp = wrow + jj * WPAD;     // uniform -> s_load x2
#pragma unroll
            for (int o = 0; o < NOFF; ++o) {
                float sw = wp[o];
#pragma unroll
                for (int r = 0; r < ROWS; ++r)
                    acc[o][r] = fmaf(xr[r + dh][dw], sw, acc[o][r]);
            }
        }
    }

    // reduce over 8 waves, one row at a time (LDS reuse)
    for (int r = 0; r < ROWS; ++r) {
#pragma unroll
        for (int o = 0; o < NOFF; ++o)
            sred[(o * WPB + wv) * 64 + w] = acc[o][r];
        __syncthreads();
        for (int item = tid; item < NOFF * 64; item += 512) {
            int o = item >> 6, p = item & 63;
            float s = 0.f;
#pragma unroll
            for (int u = 0; u < WPB; ++u) s += sred[(o * WPB + u) * 64 + p];
            part[((size_t)(q * NOFF + o)) * NPIX + b * HW + (h0 + r) * 64 + p] = s;
        }
        __syncthreads();
    }
}

// ---------------------------------------------------------------------------
// K1b: sum 4 quarter-partials, add bias, transform to pixel coords.
// ---------------------------------------------------------------------------
__global__ __launch_bounds__(256) void reduce_grid_kernel(
    const float* __restrict__ part, const float* __restrict__ offb,
    float2* __restrict__ grid2)
{
    int pixel = blockIdx.x * 256 + threadIdx.x;
    int t = blockIdx.y;
    float sx = offb[t], sy = offb[t + K2];
#pragma unroll
    for (int q = 0; q < NQ; ++q) {
        sx += part[((size_t)(q * NOFF + t)) * NPIX + pixel];
        sy += part[((size_t)(q * NOFF + t + K2)) * NPIX + pixel];
    }
    int w = pixel & 63, h = (pixel >> 6) & 63, b = pixel >> 12;
    float base_x = -1.f + (2.f / (WW - 1)) * (float)w;
    float base_y = -1.f + (2.f / (HH - 1)) * (float)h;
    float gx = ((sx + base_x + 1.f) * (float)WW - 1.f) * 0.5f;
    float gy = ((sy + base_y + 1.f) * (float)HH - 1.f) * 0.5f;
    grid2[((size_t)(b * K2 + t)) * HW + (pixel & (HW - 1))] = make_float2(gx, gy);
}

// ---------------------------------------------------------------------------
// K0: transpose x [B,C,H,W] -> xT [B,H*W,C]
// ---------------------------------------------------------------------------
__global__ __launch_bounds__(256) void transpose_kernel(
    const float* __restrict__ x, float* __restrict__ xT)
{
    __shared__ float tile[32][33];
    int b  = blockIdx.z;
    int c0 = blockIdx.y * 32;
    int p0 = blockIdx.x * 32;
    int tx = threadIdx.x;
    int ty = threadIdx.y;
#pragma unroll
    for (int i = 0; i < 4; ++i)
        tile[ty + i * 8][tx] = x[((size_t)(b * CC + c0 + ty + i * 8)) * HW + p0 + tx];
    __syncthreads();
#pragma unroll
    for (int i = 0; i < 4; ++i)
        xT[((size_t)b * HW + p0 + ty + i * 8) * CC + c0 + tx] = tile[tx][ty + i * 8];
}

// ---------------------------------------------------------------------------
// K2: bilinear sample + tap-weighted sum, float4 channel packing.
// ---------------------------------------------------------------------------
__global__ __launch_bounds__(256) void sample_kernel(
    const float* __restrict__ xT, const float2* __restrict__ grid2,
    const float* __restrict__ wk, float* __restrict__ out)
{
    __shared__ float4 recW[144];
    __shared__ int2   recI[144];
    __shared__ float  swkT[K2 * CC];
    __shared__ float  acc_s[16 * 132];

    int j = blockIdx.x;            // 0..2047
    int b = j & 7;
    int rem_base = (j >> 3) * 16;
    int h  = rem_base >> 6;
    int w0 = rem_base & 63;
    int tid = threadIdx.x;

    for (int i = tid; i < K2 * CC; i += 256) {
        int c = i / 9, t = i - c * 9;
        swkT[t * CC + c] = wk[i];
    }

    if (tid < 144) {
        int slot = tid & 15;
        int tap  = tid >> 4;
        float2 g = grid2[((size_t)(b * K2 + tap)) * HW + rem_base + slot];
        float gx = g.x, gy = g.y;
        float x0f = floorf(gx), y0f = floorf(gy);
        float wx1 = gx - x0f, wx0 = 1.f - wx1;
        float wy1 = gy - y0f, wy0 = 1.f - wy1;
        int ix0 = (int)x0f, iy0 = (int)y0f;
        int ix1 = ix0 + 1,  iy1 = iy0 + 1;
        float ax0 = ((unsigned)ix0 < WW) ? wx0 : 0.f;
        float ax1 = ((unsigned)ix1 < WW) ? wx1 : 0.f;
        float ay0 = ((unsigned)iy0 < HH) ? wy0 : 0.f;
        float ay1 = ((unsigned)iy1 < HH) ? wy1 : 0.f;
        int cx0 = min(max(ix0, 0), WW - 1), cx1 = min(max(ix1, 0), WW - 1);
        int cy0 = min(max(iy0, 0), HH - 1), cy1 = min(max(iy1, 0), HH - 1);
        int o00 = cy0 * WW + cx0, o10 = cy0 * WW + cx1;
        int o01 = cy1 * WW + cx0, o11 = cy1 * WW + cx1;
        recW[tid] = make_float4(ax0 * ay0, ax1 * ay0, ax0 * ay1, ax1 * ay1);
        recI[tid] = make_int2(o00 | (o10 << 16), o01 | (o11 << 16));
    }
    __syncthreads();

    int c4  = (tid & 31) * 4;
    int sl0 = tid >> 5;

    float4 wk4[K2];
#pragma unroll
    for (int t = 0; t < K2; ++t)
        wk4[t] = *(const float4*)&swkT[t * CC + c4];

    const float* xb = xT + (size_t)b * HW * CC;

#pragma unroll
    for (int pp = 0; pp < 2; ++pp) {
        int slot = pp * 8 + sl0;
        float4 acc = make_float4(0.f, 0.f, 0.f, 0.f);
#pragma unroll
        for (int t = 0; t < K2; ++t) {
            int r = t * 16 + slot;
            float4 wv = recW[r];
            int2   iv = recI[r];
            float4 v00 = *(const float4*)(xb + ((iv.x & 0xFFFF) << 7) + c4);
            float4 v10 = *(const float4*)(xb + ((iv.x >> 16)     << 7) + c4);
            float4 v01 = *(const float4*)(xb + ((iv.y & 0xFFFF) << 7) + c4);
            float4 v11 = *(const float4*)(xb + ((iv.y >> 16)     << 7) + c4);
            float bx0 = fmaf(v00.x, wv.x, fmaf(v10.x, wv.y, fmaf(v01.x, wv.z, v11.x * wv.w)));
            float bx1 = fmaf(v00.y, wv.x, fmaf(v10.y, wv.y, fmaf(v01.y, wv.z, v11.y * wv.w)));
            float bx2 = fmaf(v00.z, wv.x, fmaf(v10.z, wv.y, fmaf(v01.z, wv.z, v11.z * wv.w)));
            float bx3 = fmaf(v00.w, wv.x, fmaf(v10.w, wv.y, fmaf(v01.w, wv.z, v11.w * wv.w)));
            acc.x = fmaf(bx0, wk4[t].x, acc.x);
            acc.y = fmaf(bx1, wk4[t].y, acc.y);
            acc.z = fmaf(bx2, wk4[t].z, acc.z);
            acc.w = fmaf(bx3, wk4[t].w, acc.w);
        }
        *(float4*)&acc_s[slot * 132 + c4] = acc;
    }
    __syncthreads();
#pragma unroll
    for (int r = 0; r < 8; ++r) {
        int cs   = r * 16 + (tid >> 4);
        int wloc = tid & 15;
        out[((size_t)(b * CC + cs)) * HW + h * WW + w0 + wloc] = acc_s[wloc * 132 + cs];
    }
}

// ---------------------------------------------------------------------------
// Fallback (round-1 pipeline, needs only 2.36 MB ws) — defensive only.
// ---------------------------------------------------------------------------
__global__ __launch_bounds__(256) void offset_grid_kernel_fb(
    const float* __restrict__ x, const float* __restrict__ offw,
    const float* __restrict__ offb, float* __restrict__ grid)
{
    int idx = blockIdx.x * blockDim.x + threadIdx.x;
    if (idx >= NPIX) return;
    int w = idx & 63, h = (idx >> 6) & 63, b = idx >> 12;
    float acc[NOFF];
#pragma unroll
    for (int o = 0; o < NOFF; ++o) acc[o] = offb[o];
    for (int c = 0; c < CC; ++c) {
        const float* xp = x + ((size_t)(b * CC + c)) * HW;
        float xv[9];
#pragma unroll
        for (int dh = -1; dh <= 1; ++dh)
#pragma unroll
            for (int dw = -1; dw <= 1; ++dw) {
                int hh = h + dh, ww2 = w + dw;
                float v = 0.f;
                if (hh >= 0 && hh < HH && ww2 >= 0 && ww2 < WW) v = xp[hh * WW + ww2];
                xv[(dh + 1) * 3 + (dw + 1)] = v;
            }
#pragma unroll
        for (int o = 0; o < NOFF; ++o) {
            const float* wp = offw + (size_t)(o * CC + c) * 9;
#pragma unroll
            for (int jj = 0; jj < 9; ++jj) acc[o] = fmaf(xv[jj], wp[jj], acc[o]);
        }
    }
    float base_x = -1.f + (2.f / (WW - 1)) * (float)w;
    float base_y = -1.f + (2.f / (HH - 1)) * (float)h;
#pragma unroll
    for (int t = 0; t < K2; ++t) {
        float gx = ((acc[t]      + base_x + 1.f) * (float)WW - 1.f) * 0.5f;
        float gy = ((acc[K2 + t] + base_y + 1.f) * (float)HH - 1.f) * 0.5f;
        size_t gi = ((((size_t)b * K2 + t) * HH + h) * WW + w) * 2;
        grid[gi] = gx; grid[gi + 1] = gy;
    }
}

__global__ __launch_bounds__(256) void sample_kernel_fb(
    const float* __restrict__ x, const float* __restrict__ grid,
    const float* __restrict__ wk, float* __restrict__ out)
{
    int idx = blockIdx.x * blockDim.x + threadIdx.x;
    if (idx >= BB * CC * HW) return;
    int w = idx & 63, h = (idx >> 6) & 63;
    int c = (idx / HW) & 127, b = idx / (CC * HW);
    const float* xp = x + ((size_t)(b * CC + c)) * HW;
    const float2* gp = (const float2*)grid;
    float acc = 0.f;
#pragma unroll
    for (int t = 0; t < K2; ++t) {
        float2 g = gp[(((size_t)b * K2 + t)) * HW + h * WW + w];
        float gx = g.x, gy = g.y;
        float x0f = floorf(gx), y0f = floorf(gy);
        float wx1 = gx - x0f, wx0 = 1.f - wx1;
        float wy1 = gy - y0f, wy0 = 1.f - wy1;
        int ix0 = (int)x0f, iy0 = (int)y0f;
        int ix1 = ix0 + 1,  iy1 = iy0 + 1;
        float v00 = 0.f, v10 = 0.f, v01 = 0.f, v11 = 0.f;
        if ((unsigned)iy0 < HH) {
            const float* row = xp + (size_t)iy0 * WW;
            if ((unsigned)ix0 < WW) v00 = row[ix0];
            if ((unsigned)ix1 < WW) v10 = row[ix1];
        }
        if ((unsigned)iy1 < HH) {
            const float* row = xp + (size_t)iy1 * WW;
            if ((unsigned)ix0 < WW) v01 = row[ix0];
            if ((unsigned)ix1 < WW) v11 = row[ix1];
        }
        float bil = v00 * (wx0 * wy0) + v10 * (wx1 * wy0)
                  + v01 * (wx0 * wy1) + v11 * (wx1 * wy1);
        acc = fmaf(bil, wk[c * K2 + t], acc);
    }
    out[idx] = acc;
}

extern "C" void kernel_launch(void* const* d_in, const int* in_sizes, int n_in,
                              void* d_out, int out_size, void* d_ws, size_t ws_size,
                              hipStream_t stream) {
    const float* x    = (const float*)d_in[0];
    const float* offw = (const float*)d_in[1];
    const float* offb = (const float*)d_in[2];
    const float* wwk  = (const float*)d_in[3];
    float* out = (float*)d_out;

    const size_t GRID_BYTES = (size_t)NPIX * K2 * 2 * sizeof(float);   // 2.36 MB
    const size_t XT_BYTES   = (size_t)NPIX * CC * sizeof(float);       // 16.8 MB
    const size_t NEED = GRID_BYTES + XT_BYTES;                         // 19.2 MB

    if (ws_size < NEED) {
        float* grid = (float*)d_ws;
        hipLaunchKernelGGL(offset_grid_kernel_fb, dim3(NPIX / 256), dim3(256),
                           0, stream, x, offw, offb, grid);
        hipLaunchKernelGGL(sample_kernel_fb, dim3((BB * CC * HW) / 256), dim3(256),
                           0, stream, x, grid, wwk, out);
        return;
    }

    // ws layout:
    //   [0, 2.36 MB)        : wTp (92 KB, dead after offset_partial) then grid2
    //   [2.36, 19.2 MB)     : part (9.4 MB, dead after reduce) then xT (16.8 MB)
    float2* grid2 = (float2*)d_ws;
    float*  wTp   = (float*)d_ws;
    float*  region = (float*)((char*)d_ws + GRID_BYTES);
    float*  part = region;
    float*  xT   = region;

    hipLaunchKernelGGL(wtrans_kernel, dim3((NOFF * CC * 9 + 255) / 256), dim3(256),
                       0, stream, offw, wTp);
    hipLaunchKernelGGL(offset_partial_kernel, dim3(128, NQ), dim3(512),
                       0, stream, x, wTp, part);
    hipLaunchKernelGGL(reduce_grid_kernel, dim3(NPIX / 256, K2), dim3(256),
                       0, stream, part, offb, grid2);
    hipLaunchKernelGGL(transpose_kernel, dim3(HW / 32, CC / 32, BB), dim3(32, 8),
                       0, stream, x, xT);
    hipLaunchKernelGGL(sample_kernel, dim3(NPIX / 16), dim3(256),
                       0, stream, xT, grid2, wwk, out);
}

// Round 6
// 76.058 us; speedup vs baseline: 1.3513x; 1.3513x over previous
//
#include <hip/hip_runtime.h>

#define BB 8
#define CC 128
#define HH 64
#define WW 64
#define K2 9
#define NOFF 18
#define HW 4096          // HH*WW
#define NPIX 32768       // BB*HW
#define NQ 4             // channel quarter-groups (blockIdx.y)
#define ROWS 2           // pixel rows per lane (acc[18][2]=36 regs, no spill)
#define WPB 4            // waves per block
#define CPW 8            // channels per wave
#define WPAD 20          // padded weight row (18 used, 80 B stride)

// ---------------------------------------------------------------------------
// K-1: transpose offset weights [18][1152] -> wTp[k=(c,j)][WPAD] so the 18
// output weights per k are contiguous (72 B, 16B-aligned) -> 2 s_loads.
// ---------------------------------------------------------------------------
__global__ __launch_bounds__(256) void wtrans_kernel(
    const float* __restrict__ offw, float* __restrict__ wTp)
{
    int i = blockIdx.x * 256 + threadIdx.x;
    if (i >= NOFF * CC * 9) return;
    int k = i / NOFF, o = i - k * NOFF;
    wTp[k * WPAD + o] = offw[(size_t)o * CC * 9 + k];
}

// ---------------------------------------------------------------------------
// K1: offset-conv partials. Grid (256, 4): b = x&7 (XCD-local), strip = x>>3.
// Block = 256 thr = 4 waves; wave wv owns channels q*32+wv*8..+7 and a
// 2-row x 64-col pixel tile. Per (cc,jj): one contiguous 72 B weight run
// (2 s_loads, SGPR destinations) feeds 18 o x 2 rows = 36 v_fmac; 9
// independent jj groups give the scheduler prefetch slack. LDS reduce over
// 4 waves -> per-quarter partials. Live VGPRs ~70 (fits 128 cap, no spill).
// ---------------------------------------------------------------------------
__global__ __launch_bounds__(256, 4) void offset_partial_kernel(
    const float* __restrict__ x, const float* __restrict__ wTp,
    float* __restrict__ part)
{
    __shared__ float sred[NOFF * WPB * 64];   // 18 KB
    int jx = blockIdx.x;           // 0..255
    int b = jx & 7;
    int h0 = (jx >> 3) * ROWS;     // 0..62
    int q = blockIdx.y;            // 0..3
    int tid = threadIdx.x;
    int w = tid & 63;
    int wv = __builtin_amdgcn_readfirstlane(tid >> 6);  // 0..3
    int cbase = q * 32 + wv * CPW;

    float acc[NOFF][ROWS];
#pragma unroll
    for (int o = 0; o < NOFF; ++o)
#pragma unroll
        for (int r = 0; r < ROWS; ++r) acc[o][r] = 0.f;

#pragma unroll 1
    for (int cc = 0; cc < CPW; ++cc) {
        int c = cbase + cc;
        const float* xp = x + ((size_t)(b * CC + c)) * HW;
        // (ROWS+2) rows x 3 cols of x around the 2-row tile
        float xr[ROWS + 2][3];
#pragma unroll
        for (int rr = 0; rr < ROWS + 2; ++rr) {
            int hh = h0 + rr - 1;
            bool hok = (unsigned)hh < HH;
#pragma unroll
            for (int dc = 0; dc < 3; ++dc) {
                int ww2 = w + dc - 1;
                bool ok = hok && ((unsigned)ww2 < WW);
                xr[rr][dc] = ok ? xp[hh * WW + ww2] : 0.f;
            }
        }
        const float* wrow = wTp + (size_t)c * 9 * WPAD;
#pragma unroll
        for (int jj = 0; jj < 9; ++jj) {
            const int dh = jj / 3, dw = jj % 3;     // compile-time
            const float* wp = wrow + jj * WPAD;     // uniform -> 2 s_loads
#pragma unroll
            for (int o = 0; o < NOFF; ++o) {
                float sw = wp[o];
#pragma unroll
                for (int r = 0; r < ROWS; ++r)
                    acc[o][r] = fmaf(xr[r + dh][dw], sw, acc[o][r]);
            }
        }
    }

    // reduce over 4 waves, one row at a time (LDS reuse)
    for (int r = 0; r < ROWS; ++r) {
#pragma unroll
        for (int o = 0; o < NOFF; ++o)
            sred[(o * WPB + wv) * 64 + w] = acc[o][r];
        __syncthreads();
        for (int item = tid; item < NOFF * 64; item += 256) {
            int o = item >> 6, p = item & 63;
            float s = 0.f;
#pragma unroll
            for (int u = 0; u < WPB; ++u) s += sred[(o * WPB + u) * 64 + p];
            part[((size_t)(q * NOFF + o)) * NPIX + b * HW + (h0 + r) * 64 + p] = s;
        }
        __syncthreads();
    }
}

// ---------------------------------------------------------------------------
// K1b: sum 4 quarter-partials, add bias, transform to pixel coords.
// ---------------------------------------------------------------------------
__global__ __launch_bounds__(256) void reduce_grid_kernel(
    const float* __restrict__ part, const float* __restrict__ offb,
    float2* __restrict__ grid2)
{
    int pixel = blockIdx.x * 256 + threadIdx.x;
    int t = blockIdx.y;
    float sx = offb[t], sy = offb[t + K2];
#pragma unroll
    for (int q = 0; q < NQ; ++q) {
        sx += part[((size_t)(q * NOFF + t)) * NPIX + pixel];
        sy += part[((size_t)(q * NOFF + t + K2)) * NPIX + pixel];
    }
    int w = pixel & 63, h = (pixel >> 6) & 63, b = pixel >> 12;
    float base_x = -1.f + (2.f / (WW - 1)) * (float)w;
    float base_y = -1.f + (2.f / (HH - 1)) * (float)h;
    float gx = ((sx + base_x + 1.f) * (float)WW - 1.f) * 0.5f;
    float gy = ((sy + base_y + 1.f) * (float)HH - 1.f) * 0.5f;
    grid2[((size_t)(b * K2 + t)) * HW + (pixel & (HW - 1))] = make_float2(gx, gy);
}

// ---------------------------------------------------------------------------
// K0: transpose x [B,C,H,W] -> xT [B,H*W,C]
// ---------------------------------------------------------------------------
__global__ __launch_bounds__(256) void transpose_kernel(
    const float* __restrict__ x, float* __restrict__ xT)
{
    __shared__ float tile[32][33];
    int b  = blockIdx.z;
    int c0 = blockIdx.y * 32;
    int p0 = blockIdx.x * 32;
    int tx = threadIdx.x;
    int ty = threadIdx.y;
#pragma unroll
    for (int i = 0; i < 4; ++i)
        tile[ty + i * 8][tx] = x[((size_t)(b * CC + c0 + ty + i * 8)) * HW + p0 + tx];
    __syncthreads();
#pragma unroll
    for (int i = 0; i < 4; ++i)
        xT[((size_t)b * HW + p0 + ty + i * 8) * CC + c0 + tx] = tile[tx][ty + i * 8];
}

// ---------------------------------------------------------------------------
// K2: bilinear sample + tap-weighted sum, float4 channel packing.
// ---------------------------------------------------------------------------
__global__ __launch_bounds__(256) void sample_kernel(
    const float* __restrict__ xT, const float2* __restrict__ grid2,
    const float* __restrict__ wk, float* __restrict__ out)
{
    __shared__ float4 recW[144];
    __shared__ int2   recI[144];
    __shared__ float  swkT[K2 * CC];
    __shared__ float  acc_s[16 * 132];

    int j = blockIdx.x;            // 0..2047
    int b = j & 7;
    int rem_base = (j >> 3) * 16;
    int h  = rem_base >> 6;
    int w0 = rem_base & 63;
    int tid = threadIdx.x;

    for (int i = tid; i < K2 * CC; i += 256) {
        int c = i / 9, t = i - c * 9;
        swkT[t * CC + c] = wk[i];
    }

    if (tid < 144) {
        int slot = tid & 15;
        int tap  = tid >> 4;
        float2 g = grid2[((size_t)(b * K2 + tap)) * HW + rem_base + slot];
        float gx = g.x, gy = g.y;
        float x0f = floorf(gx), y0f = floorf(gy);
        float wx1 = gx - x0f, wx0 = 1.f - wx1;
        float wy1 = gy - y0f, wy0 = 1.f - wy1;
        int ix0 = (int)x0f, iy0 = (int)y0f;
        int ix1 = ix0 + 1,  iy1 = iy0 + 1;
        float ax0 = ((unsigned)ix0 < WW) ? wx0 : 0.f;
        float ax1 = ((unsigned)ix1 < WW) ? wx1 : 0.f;
        float ay0 = ((unsigned)iy0 < HH) ? wy0 : 0.f;
        float ay1 = ((unsigned)iy1 < HH) ? wy1 : 0.f;
        int cx0 = min(max(ix0, 0), WW - 1), cx1 = min(max(ix1, 0), WW - 1);
        int cy0 = min(max(iy0, 0), HH - 1), cy1 = min(max(iy1, 0), HH - 1);
        int o00 = cy0 * WW + cx0, o10 = cy0 * WW + cx1;
        int o01 = cy1 * WW + cx0, o11 = cy1 * WW + cx1;
        recW[tid] = make_float4(ax0 * ay0, ax1 * ay0, ax0 * ay1, ax1 * ay1);
        recI[tid] = make_int2(o00 | (o10 << 16), o01 | (o11 << 16));
    }
    __syncthreads();

    int c4  = (tid & 31) * 4;
    int sl0 = tid >> 5;

    float4 wk4[K2];
#pragma unroll
    for (int t = 0; t < K2; ++t)
        wk4[t] = *(const float4*)&swkT[t * CC + c4];

    const float* xb = xT + (size_t)b * HW * CC;

#pragma unroll
    for (int pp = 0; pp < 2; ++pp) {
        int slot = pp * 8 + sl0;
        float4 acc = make_float4(0.f, 0.f, 0.f, 0.f);
#pragma unroll
        for (int t = 0; t < K2; ++t) {
            int r = t * 16 + slot;
            float4 wv = recW[r];
            int2   iv = recI[r];
            float4 v00 = *(const float4*)(xb + ((iv.x & 0xFFFF) << 7) + c4);
            float4 v10 = *(const float4*)(xb + ((iv.x >> 16)     << 7) + c4);
            float4 v01 = *(const float4*)(xb + ((iv.y & 0xFFFF) << 7) + c4);
            float4 v11 = *(const float4*)(xb + ((iv.y >> 16)     << 7) + c4);
            float bx0 = fmaf(v00.x, wv.x, fmaf(v10.x, wv.y, fmaf(v01.x, wv.z, v11.x * wv.w)));
            float bx1 = fmaf(v00.y, wv.x, fmaf(v10.y, wv.y, fmaf(v01.y, wv.z, v11.y * wv.w)));
            float bx2 = fmaf(v00.z, wv.x, fmaf(v10.z, wv.y, fmaf(v01.z, wv.z, v11.z * wv.w)));
            float bx3 = fmaf(v00.w, wv.x, fmaf(v10.w, wv.y, fmaf(v01.w, wv.z, v11.w * wv.w)));
            acc.x = fmaf(bx0, wk4[t].x, acc.x);
            acc.y = fmaf(bx1, wk4[t].y, acc.y);
            acc.z = fmaf(bx2, wk4[t].z, acc.z);
            acc.w = fmaf(bx3, wk4[t].w, acc.w);
        }
        *(float4*)&acc_s[slot * 132 + c4] = acc;
    }
    __syncthreads();
#pragma unroll
    for (int r = 0; r < 8; ++r) {
        int cs   = r * 16 + (tid >> 4);
        int wloc = tid & 15;
        out[((size_t)(b * CC + cs)) * HW + h * WW + w0 + wloc] = acc_s[wloc * 132 + cs];
    }
}

// ---------------------------------------------------------------------------
// Fallback (round-1 pipeline, needs only 2.36 MB ws) — defensive only.
// ---------------------------------------------------------------------------
__global__ __launch_bounds__(256) void offset_grid_kernel_fb(
    const float* __restrict__ x, const float* __restrict__ offw,
    const float* __restrict__ offb, float* __restrict__ grid)
{
    int idx = blockIdx.x * blockDim.x + threadIdx.x;
    if (idx >= NPIX) return;
    int w = idx & 63, h = (idx >> 6) & 63, b = idx >> 12;
    float acc[NOFF];
#pragma unroll
    for (int o = 0; o < NOFF; ++o) acc[o] = offb[o];
    for (int c = 0; c < CC; ++c) {
        const float* xp = x + ((size_t)(b * CC + c)) * HW;
        float xv[9];
#pragma unroll
        for (int dh = -1; dh <= 1; ++dh)
#pragma unroll
            for (int dw = -1; dw <= 1; ++dw) {
                int hh = h + dh, ww2 = w + dw;
                float v = 0.f;
                if (hh >= 0 && hh < HH && ww2 >= 0 && ww2 < WW) v = xp[hh * WW + ww2];
                xv[(dh + 1) * 3 + (dw + 1)] = v;
            }
#pragma unroll
        for (int o = 0; o < NOFF; ++o) {
            const float* wp = offw + (size_t)(o * CC + c) * 9;
#pragma unroll
            for (int jj = 0; jj < 9; ++jj) acc[o] = fmaf(xv[jj], wp[jj], acc[o]);
        }
    }
    float base_x = -1.f + (2.f / (WW - 1)) * (float)w;
    float base_y = -1.f + (2.f / (HH - 1)) * (float)h;
#pragma unroll
    for (int t = 0; t < K2; ++t) {
        float gx = ((acc[t]      + base_x + 1.f) * (float)WW - 1.f) * 0.5f;
        float gy = ((acc[K2 + t] + base_y + 1.f) * (float)HH - 1.f) * 0.5f;
        size_t gi = ((((size_t)b * K2 + t) * HH + h) * WW + w) * 2;
        grid[gi] = gx; grid[gi + 1] = gy;
    }
}

__global__ __launch_bounds__(256) void sample_kernel_fb(
    const float* __restrict__ x, const float* __restrict__ grid,
    const float* __restrict__ wk, float* __restrict__ out)
{
    int idx = blockIdx.x * blockDim.x + threadIdx.x;
    if (idx >= BB * CC * HW) return;
    int w = idx & 63, h = (idx >> 6) & 63;
    int c = (idx / HW) & 127, b = idx / (CC * HW);
    const float* xp = x + ((size_t)(b * CC + c)) * HW;
    const float2* gp = (const float2*)grid;
    float acc = 0.f;
#pragma unroll
    for (int t = 0; t < K2; ++t) {
        float2 g = gp[(((size_t)b * K2 + t)) * HW + h * WW + w];
        float gx = g.x, gy = g.y;
        float x0f = floorf(gx), y0f = floorf(gy);
        float wx1 = gx - x0f, wx0 = 1.f - wx1;
        float wy1 = gy - y0f, wy0 = 1.f - wy1;
        int ix0 = (int)x0f, iy0 = (int)y0f;
        int ix1 = ix0 + 1,  iy1 = iy0 + 1;
        float v00 = 0.f, v10 = 0.f, v01 = 0.f, v11 = 0.f;
        if ((unsigned)iy0 < HH) {
            const float* row = xp + (size_t)iy0 * WW;
            if ((unsigned)ix0 < WW) v00 = row[ix0];
            if ((unsigned)ix1 < WW) v10 = row[ix1];
        }
        if ((unsigned)iy1 < HH) {
            const float* row = xp + (size_t)iy1 * WW;
            if ((unsigned)ix0 < WW) v01 = row[ix0];
            if ((unsigned)ix1 < WW) v11 = row[ix1];
        }
        float bil = v00 * (wx0 * wy0) + v10 * (wx1 * wy0)
                  + v01 * (wx0 * wy1) + v11 * (wx1 * wy1);
        acc = fmaf(bil, wk[c * K2 + t], acc);
    }
    out[idx] = acc;
}

extern "C" void kernel_launch(void* const* d_in, const int* in_sizes, int n_in,
                              void* d_out, int out_size, void* d_ws, size_t ws_size,
                              hipStream_t stream) {
    const float* x    = (const float*)d_in[0];
    const float* offw = (const float*)d_in[1];
    const float* offb = (const float*)d_in[2];
    const float* wwk  = (const float*)d_in[3];
    float* out = (float*)d_out;

    const size_t GRID_BYTES = (size_t)NPIX * K2 * 2 * sizeof(float);   // 2.36 MB
    const size_t XT_BYTES   = (size_t)NPIX * CC * sizeof(float);       // 16.8 MB
    const size_t NEED = GRID_BYTES + XT_BYTES;                         // 19.2 MB

    if (ws_size < NEED) {
        float* grid = (float*)d_ws;
        hipLaunchKernelGGL(offset_grid_kernel_fb, dim3(NPIX / 256), dim3(256),
                           0, stream, x, offw, offb, grid);
        hipLaunchKernelGGL(sample_kernel_fb, dim3((BB * CC * HW) / 256), dim3(256),
                           0, stream, x, grid, wwk, out);
        return;
    }

    // ws layout:
    //   [0, 2.36 MB)    : wTp (92 KB, dead after offset_partial) then grid2
    //   [2.36, 19.2 MB) : part (9.4 MB, dead after reduce) then xT (16.8 MB)
    float2* grid2 = (float2*)d_ws;
    float*  wTp   = (float*)d_ws;
    float*  region = (float*)((char*)d_ws + GRID_BYTES);
    float*  part = region;
    float*  xT   = region;

    hipLaunchKernelGGL(wtrans_kernel, dim3((NOFF * CC * 9 + 255) / 256), dim3(256),
                       0, stream, offw, wTp);
    hipLaunchKernelGGL(offset_partial_kernel, dim3(256, NQ), dim3(256),
                       0, stream, x, wTp, part);
    hipLaunchKernelGGL(reduce_grid_kernel, dim3(NPIX / 256, K2), dim3(256),
                       0, stream, part, offb, grid2);
    hipLaunchKernelGGL(transpose_kernel, dim3(HW / 32, CC / 32, BB), dim3(32, 8),
                       0, stream, x, xT);
    hipLaunchKernelGGL(sample_kernel, dim3(NPIX / 16), dim3(256),
                       0, stream, xT, grid2, wwk, out);
}